// Round 13
// baseline (114.661 us; speedup 1.0000x reference)
//
#include <hip/hip_runtime.h>
#include <hip/hip_bf16.h>

#define TRAJ 50

typedef __attribute__((ext_vector_type(8))) short short8;
typedef __attribute__((ext_vector_type(4))) float f32x4;
typedef __attribute__((ext_vector_type(2))) float f32x2;

#if defined(__has_builtin)
#if __has_builtin(__builtin_amdgcn_exp2f)
#define EXP2F(x) __builtin_amdgcn_exp2f(x)
#else
#define EXP2F(x) exp2f(x)
#endif
#if __has_builtin(__builtin_amdgcn_rcpf)
#define RCPF(x) __builtin_amdgcn_rcpf(x)
#else
#define RCPF(x) (1.0f/(x))
#endif
#else
#define EXP2F(x) exp2f(x)
#define RCPF(x) (1.0f/(x))
#endif

// LDS-only fused barrier (verified rounds 6/8/11): no schedulable gap between
// the lgkm wait and s_barrier; does NOT drain global stores (vmcnt).
#define BAR() asm volatile("s_waitcnt lgkmcnt(0)\n\ts_barrier" ::: "memory")

__device__ __forceinline__ unsigned short f2bf(float f){
  union { float f; unsigned u; } v; v.f = f;
  unsigned u = v.u;
  u += 0x7FFFu + ((u >> 16) & 1u);   // RNE
  return (unsigned short)(u >> 16);
}
__device__ __forceinline__ unsigned pk(unsigned short a, unsigned short b){
  return (unsigned)a | ((unsigned)b << 16);
}
__device__ __forceinline__ unsigned pkbf(float a, float b){
  union { __hip_bfloat162 h; unsigned u; } c;
  c.h = __float22bfloat162_rn(make_float2(a, b));   // v_cvt_pk_bf16_f32
  return c.u;
}

#define MFMA16(A,B,C) __builtin_amdgcn_mfma_f32_16x16x32_bf16((A),(B),(C),0,0,0)

#define SSC (-1.44269504f)   // sigmoid scale: sigma(x) = 1/(1+2^(SSC*x))
#define TSC ( 2.88539008f)   // tanh scale:   tanh(y)  = 1-2/(1+2^(TSC*y))

__device__ __forceinline__ f32x2 exp2v(f32x2 v){ return (f32x2){EXP2F(v[0]), EXP2F(v[1])}; }
__device__ __forceinline__ f32x2 rcpv (f32x2 v){ return (f32x2){RCPF(v[0]), RCPF(v[1])}; }

// per element pair: r/u sigmoids share one rcp; tanh via exp2+rcp.
// (round-2/6/8/11 math, verified absmax 0.125)
__device__ __forceinline__ f32x2 gru_pair(f32x2 r_, f32x2 u_, f32x2 n_, f32x2 i_, f32x2 hp){
  const f32x2 one = (f32x2){1.f, 1.f};
  f32x2 d1 = exp2v(r_) + one;
  f32x2 d2 = exp2v(u_) + one;
  f32x2 rp = rcpv(d1 * d2);
  f32x2 rv = d2 * rp;                               // sigma(arg_r)
  f32x2 uv = d1 * rp;                               // sigma(arg_u)
  f32x2 y  = __builtin_elementwise_fma(rv, n_, i_); // TSC*(inn + r*hn)
  f32x2 nv = one - 2.f * rcpv(exp2v(y) + one);      // tanh
  return __builtin_elementwise_fma(uv, hp - nv, nv);
}

// gather an A fragment directly from a global row-major [K][N] f32 matrix:
// frag elements = scale * M[k0+j][i], j=0..7 (k0 = kb*32 + lg*8), i = row index.
// Proven (r7/r8): lane holds k-elems lg*8..lg*8+7 of its 32-k block.
__device__ __forceinline__ short8 gatherA(const float* __restrict__ M, int N,
                                          int k0, int i, float scale){
  const float* qp = M + (size_t)k0 * N + i;
  union { unsigned u[4]; short8 s; } c;
  #pragma unroll
  for (int j = 0; j < 4; ++j){
    float a = qp[(2*j  ) * N];
    float b = qp[(2*j+1) * N];
    c.u[j] = pk(f2bf(scale * a), f2bf(scale * b));
  }
  return c.s;
}

// DECORRELATED QUAD-SPLIT, register-slimmed: Ak2/AoR fragments (24 regs of
// loop-LIVE state) demoted to a compact LDS region and re-read per step as
// TRANSIENTS (RA can schedule just-in-time; loop-live regs can't be spilled
// cheaply — r10's lesson). Inactive lanes broadcast-read a zero page (free);
// active lanes stride 16B (<=2-way, free per m136). (256,5): cap 102 VGPR —
// ~85 needed after demotion, margin against r10-style loop spill.
__global__ __launch_bounds__(256, 5) void gru_actor_kernel(
    const float* __restrict__ x,
    const float* __restrict__ W1, const float* __restrict__ b1,
    const float* __restrict__ W2, const float* __restrict__ b2,
    const float* __restrict__ Wih, const float* __restrict__ bih,
    const float* __restrict__ Whh, const float* __restrict__ bhh,
    const float* __restrict__ Wout, const float* __restrict__ bout,
    float* __restrict__ out)
{
  __shared__ __align__(16) char sm_h[4096];               // [buf][16 rows][128B], XOR-swizzled
  __shared__ __align__(16) char sm_aug[1024 + 4 * 1280];  // [zero page 1024][per-wave: ak2 4x256 | aoR 2x128]

  const int t    = threadIdx.x;        // 0..255
  const int q    = t >> 6;             // wave's dim-quarter
  const int l    = t & 63;
  const int lr   = l & 15;
  const int lg   = l >> 4;
  const int rowbase = blockIdx.x * 16;
  const int dimq = q * 16;
  const int swz  = (lr & 7) << 4;
  const int colw = 32 * q + 8 * lg;    // this lane's h-write byte col (pre-XOR)

  // zero page for broadcast-reads of inactive-lane fragments (1024B, 256x4B)
  *(unsigned*)(sm_aug + t * 4) = 0u;

  // ---------------- layer 1: z1 dims [dimq,dimq+16) = relu(W1T @ xT + b1) ----------------
  f32x4 acc1;
  { float4 bv = *(const float4*)(b1 + dimq + 4 * lg);
    acc1 = (f32x4){bv.x, bv.y, bv.z, bv.w}; }
  {
    const float* xrow = x + (size_t)(rowbase + lr) * 256;
    #pragma unroll
    for (int kb = 0; kb < 8; ++kb){
      int k0 = kb * 32 + lg * 8;
      float4 xa = *(const float4*)(xrow + k0);
      float4 xb = *(const float4*)(xrow + k0 + 4);
      union { unsigned u[4]; short8 s; } bc;
      bc.u[0] = pkbf(xa.x, xa.y); bc.u[1] = pkbf(xa.z, xa.w);
      bc.u[2] = pkbf(xb.x, xb.y); bc.u[3] = pkbf(xb.z, xb.w);
      short8 A = gatherA(W1, 64, k0, dimq + lr, 1.0f);
      acc1 = MFMA16(A, bc.s, acc1);
    }
  }
  // z1 (bf16, relu) -> buf0
  *(uint2*)(sm_h + lr * 128 + (colw ^ swz)) =
      make_uint2(pkbf(fmaxf(acc1[0],0.f), fmaxf(acc1[1],0.f)),
                 pkbf(fmaxf(acc1[2],0.f), fmaxf(acc1[3],0.f)));
  __syncthreads();

  // ---------------- layer 2: h dims [dimq,dimq+16) = relu(W2T @ z1T + b2) ----------------
  f32x2 h2[2];
  {
    f32x4 acc2;
    float4 bv = *(const float4*)(b2 + dimq + 4 * lg);
    acc2 = (f32x4){bv.x, bv.y, bv.z, bv.w};
    #pragma unroll
    for (int kb = 0; kb < 2; ++kb){
      short8 B = *(const short8*)(sm_h + lr * 128 + ((kb * 64 + 16 * lg) ^ swz));
      short8 A = gatherA(W2, 64, kb * 32 + lg * 8, dimq + lr, 1.0f);
      acc2 = MFMA16(A, B, acc2);
    }
    h2[0] = (f32x2){fmaxf(acc2[0],0.f), fmaxf(acc2[1],0.f)};
    h2[1] = (f32x2){fmaxf(acc2[2],0.f), fmaxf(acc2[3],0.f)};
    // h -> buf1 (z1 reads above precede the barrier below; step0 overwrites buf0)
    *(uint2*)(sm_h + 2048 + lr * 128 + (colw ^ swz)) =
        make_uint2(pkbf(h2[0][0], h2[0][1]), pkbf(h2[1][0], h2[1][1]));
  }

  // ---------------- loop-invariant fragments ----------------
  // Ah stays in REGISTERS (used early in the MFMA chain).
  short8 Ah[3][2];    // [gate r/u/n][kb]: Whh^T rows for this wave's 16 dims
  #pragma unroll
  for (int g = 0; g < 3; ++g){
    float sc = (g < 2) ? SSC : TSC;
    #pragma unroll
    for (int kb = 0; kb < 2; ++kb)
      Ah[g][kb] = gatherA(Whh, 192, kb * 32 + lg * 8, g * 64 + dimq + lr, sc);
  }
  // Ak2 (augmented k-block: k=64 wp0, 65 wp1, 66 1.0) and Wout^T -> compact LDS.
  char* wq = sm_aug + 1024 + q * 1280;
  if (lg == 0){
    int dr = dimq + lr, du = 64 + dr, dn = 128 + dr;
    *(uint4*)(wq +   0 + lr*16) = make_uint4(pk(f2bf(SSC*Wih[dr]), f2bf(SSC*Wih[192+dr])),
                                             pk(f2bf(SSC*(bih[dr]+bhh[dr])), 0), 0u, 0u);
    *(uint4*)(wq + 256 + lr*16) = make_uint4(pk(f2bf(SSC*Wih[du]), f2bf(SSC*Wih[192+du])),
                                             pk(f2bf(SSC*(bih[du]+bhh[du])), 0), 0u, 0u);
    *(uint4*)(wq + 512 + lr*16) = make_uint4(0u, pk(f2bf(TSC*bhh[dn]), 0), 0u, 0u);
    *(uint4*)(wq + 768 + lr*16) = make_uint4(pk(f2bf(TSC*Wih[dn]), f2bf(TSC*Wih[192+dn])),
                                             pk(f2bf(TSC*bih[dn]), 0), 0u, 0u);
  }
  if (lr < 2){
    #pragma unroll
    for (int kb = 0; kb < 2; ++kb){
      unsigned w_[4];
      #pragma unroll
      for (int j4 = 0; j4 < 4; ++j4){
        int k = kb * 32 + lg * 8 + 2 * j4;
        w_[j4] = pk(f2bf(SSC * Wout[k * 2 + lr]), f2bf(SSC * Wout[(k + 1) * 2 + lr]));
      }
      *(uint4*)(wq + 1024 + kb * 128 + (lr * 4 + lg) * 16) = make_uint4(w_[0], w_[1], w_[2], w_[3]);
    }
  }
  // per-lane read offsets (inactive lanes -> zero page broadcast)
  unsigned off_ak = (lg == 0) ? (unsigned)(1024 + q * 1280 + lr * 16) : 0u;
  unsigned off_ao = (lr <  2) ? (unsigned)(1024 + q * 1280 + 1024 + (lr * 4 + lg) * 16) : 0u;

  // hoisted tail-bias init vector ({bo0,bo1,0,0} in lg==0 lanes, zeros elsewhere)
  f32x4 aD0 = (f32x4){0,0,0,0};
  if (lg == 0){ aD0[0] = SSC * bout[0]; aD0[1] = SSC * bout[1]; }
  const unsigned b2hi = (lg == 0) ? 0x00003F80u : 0u;   // 1.0bf in k=66 slot
  const bool dostore = (lg == 0 && q == 0);
  const int rd0 = lr * 128 + ((0  + 16 * lg) ^ swz);
  const int rd1 = lr * 128 + ((64 + 16 * lg) ^ swz);
  const int wr0 = lr * 128 + (colw ^ swz);
  __syncthreads();                                   // h(buf1) + aug LDS ready

  // ---------------- GRU rollout: 1 fused LDS-barrier/step, h double-buffered ----------------
  float wp0 = 0.f, wp1 = 0.f;
  float* outp = out + (size_t)(rowbase + lr) * 100;
  short8 B0 = *(const short8*)(sm_h + 2048 + rd0);
  short8 B1 = *(const short8*)(sm_h + 2048 + rd1);

  #pragma unroll 2
  for (int s = 0; s < TRAJ; ++s){
    char* bufW = sm_h + ((s & 1) << 11);   // step0 writes buf0, step1 buf1, ...
    short8 B2;
    {
      union { unsigned u[4]; short8 sv; } c;
      c.u[0] = (lg == 0) ? pkbf(wp0, wp1) : 0u;   // only the wp word varies per step
      c.u[1] = b2hi; c.u[2] = 0u; c.u[3] = 0u;
      B2 = c.sv;
    }
    // anti-LICM: keep the invariant-fragment reads inside the loop (transient regs)
    asm volatile("" : "+v"(off_ak));
    short8 AkR = *(const short8*)(sm_aug + off_ak);
    short8 AkU = *(const short8*)(sm_aug + off_ak + 256);
    short8 AkN = *(const short8*)(sm_aug + off_ak + 512);
    short8 AkI = *(const short8*)(sm_aug + off_ak + 768);
    f32x4 aR = (f32x4){0,0,0,0}, aU = (f32x4){0,0,0,0};
    f32x4 aN = (f32x4){0,0,0,0}, aI = (f32x4){0,0,0,0};
    aR = MFMA16(Ah[0][0], B0, aR);
    aR = MFMA16(Ah[0][1], B1, aR);
    aR = MFMA16(AkR,      B2, aR);
    aU = MFMA16(Ah[1][0], B0, aU);
    aU = MFMA16(Ah[1][1], B1, aU);
    aU = MFMA16(AkU,      B2, aU);
    aN = MFMA16(Ah[2][0], B0, aN);
    aN = MFMA16(Ah[2][1], B1, aN);
    aN = MFMA16(AkN,      B2, aN);
    aI = MFMA16(AkI,      B2, aI);
    f32x2 hA = gru_pair((f32x2){aR[0],aR[1]}, (f32x2){aU[0],aU[1]},
                        (f32x2){aN[0],aN[1]}, (f32x2){aI[0],aI[1]}, h2[0]);
    f32x2 hB = gru_pair((f32x2){aR[2],aR[3]}, (f32x2){aU[2],aU[3]},
                        (f32x2){aN[2],aN[3]}, (f32x2){aI[2],aI[3]}, h2[1]);
    h2[0] = hA; h2[1] = hB;
    *(uint2*)(bufW + wr0) =
        make_uint2(pkbf(hA[0], hA[1]), pkbf(hB[0], hB[1]));
    BAR();                                     // fused lgkmcnt(0)+s_barrier (LDS-only)
    asm volatile("" : "+v"(off_ao));
    short8 nB0 = *(const short8*)(bufW + rd0);
    short8 nB1 = *(const short8*)(bufW + rd1);
    short8 Ao0 = *(const short8*)(sm_aug + off_ao);
    short8 Ao1 = *(const short8*)(sm_aug + off_ao + 128);
    f32x4 aD = aD0;
    aD = MFMA16(Ao0, nB0, aD);
    aD = MFMA16(Ao1, nB1, aD);
    {
      float ea = EXP2F(aD[0]), eb = EXP2F(aD[1]);
      float da = 1.f + ea, db = 1.f + eb;
      float rp = RCPF(da * db);
      wp0 += db * rp;                          // sigmoid(dx0)
      wp1 += da * rp;                          // sigmoid(dx1)
    }
    if (dostore)
      *(float2*)(outp + 2 * s) = make_float2(wp0, wp1);
    B0 = nB0; B1 = nB1;
  }
}

extern "C" void kernel_launch(void* const* d_in, const int* in_sizes, int n_in,
                              void* d_out, int out_size, void* d_ws, size_t ws_size,
                              hipStream_t stream) {
  (void)n_in; (void)out_size; (void)d_ws; (void)ws_size;
  const float* x    = (const float*)d_in[0];
  const float* W1   = (const float*)d_in[1];
  const float* b1   = (const float*)d_in[2];
  const float* W2   = (const float*)d_in[3];
  const float* b2   = (const float*)d_in[4];
  const float* Wih  = (const float*)d_in[5];
  const float* bih  = (const float*)d_in[6];
  const float* Whh  = (const float*)d_in[7];
  const float* bhh  = (const float*)d_in[8];
  const float* Wout = (const float*)d_in[9];
  const float* bout = (const float*)d_in[10];
  float* out = (float*)d_out;

  int nrows = in_sizes[0] / 256;
  int grid  = nrows / 16;                      // one 16-row group per 256-thread block
  gru_actor_kernel<<<dim3(grid), dim3(256), 0, stream>>>(
      x, W1, b1, W2, b2, Wih, bih, Whh, bhh, Wout, bout, out);
}

// Round 14
// 111.624 us; speedup vs baseline: 1.0272x; 1.0272x over previous
//
#include <hip/hip_runtime.h>
#include <hip/hip_bf16.h>

#define TRAJ 50

typedef __attribute__((ext_vector_type(8))) short short8;
typedef __attribute__((ext_vector_type(4))) float f32x4;
typedef __attribute__((ext_vector_type(2))) float f32x2;

#if defined(__has_builtin)
#if __has_builtin(__builtin_amdgcn_exp2f)
#define EXP2F(x) __builtin_amdgcn_exp2f(x)
#else
#define EXP2F(x) exp2f(x)
#endif
#if __has_builtin(__builtin_amdgcn_rcpf)
#define RCPF(x) __builtin_amdgcn_rcpf(x)
#else
#define RCPF(x) (1.0f/(x))
#endif
#else
#define EXP2F(x) exp2f(x)
#define RCPF(x) (1.0f/(x))
#endif

// LDS-only fused barrier (verified rounds 6/8/11): no schedulable gap between
// the lgkm wait and s_barrier; does NOT drain global stores (vmcnt).
#define BAR() asm volatile("s_waitcnt lgkmcnt(0)\n\ts_barrier" ::: "memory")

__device__ __forceinline__ unsigned short f2bf(float f){
  union { float f; unsigned u; } v; v.f = f;
  unsigned u = v.u;
  u += 0x7FFFu + ((u >> 16) & 1u);   // RNE
  return (unsigned short)(u >> 16);
}
__device__ __forceinline__ unsigned pk(unsigned short a, unsigned short b){
  return (unsigned)a | ((unsigned)b << 16);
}
__device__ __forceinline__ unsigned pkbf(float a, float b){
  union { __hip_bfloat162 h; unsigned u; } c;
  c.h = __float22bfloat162_rn(make_float2(a, b));   // v_cvt_pk_bf16_f32
  return c.u;
}

#define MFMA16(A,B,C) __builtin_amdgcn_mfma_f32_16x16x32_bf16((A),(B),(C),0,0,0)

#define SSC (-1.44269504f)   // sigmoid scale: sigma(x) = 1/(1+2^(SSC*x))
#define TSC ( 2.88539008f)   // tanh scale:   tanh(y)  = 1-2/(1+2^(TSC*y))

__device__ __forceinline__ f32x2 exp2v(f32x2 v){ return (f32x2){EXP2F(v[0]), EXP2F(v[1])}; }
__device__ __forceinline__ f32x2 rcpv (f32x2 v){ return (f32x2){RCPF(v[0]), RCPF(v[1])}; }

// per element pair: r/u sigmoids share one rcp; tanh via exp2+rcp.
// (round-2/6/8/11 math, verified absmax 0.125)
__device__ __forceinline__ f32x2 gru_pair(f32x2 r_, f32x2 u_, f32x2 n_, f32x2 i_, f32x2 hp){
  const f32x2 one = (f32x2){1.f, 1.f};
  f32x2 d1 = exp2v(r_) + one;
  f32x2 d2 = exp2v(u_) + one;
  f32x2 rp = rcpv(d1 * d2);
  f32x2 rv = d2 * rp;                               // sigma(arg_r)
  f32x2 uv = d1 * rp;                               // sigma(arg_u)
  f32x2 y  = __builtin_elementwise_fma(rv, n_, i_); // TSC*(inn + r*hn)
  f32x2 nv = one - 2.f * rcpv(exp2v(y) + one);      // tanh
  return __builtin_elementwise_fma(uv, hp - nv, nv);
}

// gather an A fragment directly from a global row-major [K][N] f32 matrix:
// frag elements = scale * M[k0+j][i], j=0..7 (k0 = kb*32 + lg*8), i = row index.
// Proven (r7/r8): lane holds k-elems lg*8..lg*8+7 of its 32-k block.
__device__ __forceinline__ short8 gatherA(const float* __restrict__ M, int N,
                                          int k0, int i, float scale){
  const float* qp = M + (size_t)k0 * N + i;
  union { unsigned u[4]; short8 s; } c;
  #pragma unroll
  for (int j = 0; j < 4; ++j){
    float a = qp[(2*j  ) * N];
    float b = qp[(2*j+1) * N];
    c.u[j] = pk(f2bf(scale * a), f2bf(scale * b));
  }
  return c.s;
}

// DECORRELATED QUAD-SPLIT (round-11 configuration — empirical optimum, 110.9us):
// block = 256 thr = 4 waves = ONE 16-row group; wave q owns dims [16q,16q+16).
// (256,4): cap 128 VGPR — spill-free at 48 VGPR (r8/r11). r13's LDS demotion
// of Ak2/AoR regressed (bank conflicts 1.7M->4.2M, occupancy unchanged) —
// fragments stay in registers.
__global__ __launch_bounds__(256, 4) void gru_actor_kernel(
    const float* __restrict__ x,
    const float* __restrict__ W1, const float* __restrict__ b1,
    const float* __restrict__ W2, const float* __restrict__ b2,
    const float* __restrict__ Wih, const float* __restrict__ bih,
    const float* __restrict__ Whh, const float* __restrict__ bhh,
    const float* __restrict__ Wout, const float* __restrict__ bout,
    float* __restrict__ out)
{
  __shared__ __align__(16) char sm_h[4096];   // [buf][16 rows][128B], XOR-swizzled

  const int t    = threadIdx.x;        // 0..255
  const int q    = t >> 6;             // wave's dim-quarter
  const int l    = t & 63;
  const int lr   = l & 15;
  const int lg   = l >> 4;
  const int rowbase = blockIdx.x * 16;
  const int dimq = q * 16;
  const int swz  = (lr & 7) << 4;
  const int colw = 32 * q + 8 * lg;    // this lane's h-write byte col (pre-XOR)

  // ---------------- layer 1: z1 dims [dimq,dimq+16) = relu(W1T @ xT + b1) ----------------
  f32x4 acc1;
  { float4 bv = *(const float4*)(b1 + dimq + 4 * lg);
    acc1 = (f32x4){bv.x, bv.y, bv.z, bv.w}; }
  {
    const float* xrow = x + (size_t)(rowbase + lr) * 256;
    #pragma unroll
    for (int kb = 0; kb < 8; ++kb){
      int k0 = kb * 32 + lg * 8;
      float4 xa = *(const float4*)(xrow + k0);
      float4 xb = *(const float4*)(xrow + k0 + 4);
      union { unsigned u[4]; short8 s; } bc;
      bc.u[0] = pkbf(xa.x, xa.y); bc.u[1] = pkbf(xa.z, xa.w);
      bc.u[2] = pkbf(xb.x, xb.y); bc.u[3] = pkbf(xb.z, xb.w);
      short8 A = gatherA(W1, 64, k0, dimq + lr, 1.0f);
      acc1 = MFMA16(A, bc.s, acc1);
    }
  }
  // z1 (bf16, relu) -> buf0
  *(uint2*)(sm_h + lr * 128 + (colw ^ swz)) =
      make_uint2(pkbf(fmaxf(acc1[0],0.f), fmaxf(acc1[1],0.f)),
                 pkbf(fmaxf(acc1[2],0.f), fmaxf(acc1[3],0.f)));
  __syncthreads();

  // ---------------- layer 2: h dims [dimq,dimq+16) = relu(W2T @ z1T + b2) ----------------
  f32x2 h2[2];
  {
    f32x4 acc2;
    float4 bv = *(const float4*)(b2 + dimq + 4 * lg);
    acc2 = (f32x4){bv.x, bv.y, bv.z, bv.w};
    #pragma unroll
    for (int kb = 0; kb < 2; ++kb){
      short8 B = *(const short8*)(sm_h + lr * 128 + ((kb * 64 + 16 * lg) ^ swz));
      short8 A = gatherA(W2, 64, kb * 32 + lg * 8, dimq + lr, 1.0f);
      acc2 = MFMA16(A, B, acc2);
    }
    h2[0] = (f32x2){fmaxf(acc2[0],0.f), fmaxf(acc2[1],0.f)};
    h2[1] = (f32x2){fmaxf(acc2[2],0.f), fmaxf(acc2[3],0.f)};
    // h -> buf1 (z1 reads above precede the barrier below; step0 overwrites buf0)
    *(uint2*)(sm_h + 2048 + lr * 128 + (colw ^ swz)) =
        make_uint2(pkbf(h2[0][0], h2[0][1]), pkbf(h2[1][0], h2[1][1]));
  }

  // ---------------- loop-invariant fragments (gathered from global, pre-scaled) ----------------
  short8 Ah[3][2];    // [gate r/u/n][kb]: Whh^T rows for this wave's 16 dims
  #pragma unroll
  for (int g = 0; g < 3; ++g){
    float sc = (g < 2) ? SSC : TSC;
    #pragma unroll
    for (int kb = 0; kb < 2; ++kb)
      Ah[g][kb] = gatherA(Whh, 192, kb * 32 + lg * 8, g * 64 + dimq + lr, sc);
  }
  // augmented k-block (k=64:wp0, 65:wp1, 66:1.0) as FULL fragments (zeros hoisted)
  short8 Ak2f[4];   // [r,u,hn,inn]
  {
    union { unsigned u[4]; short8 s; } c;
    c.u[0] = c.u[1] = c.u[2] = c.u[3] = 0u;
    int dr = dimq + lr, du = 64 + dr, dn = 128 + dr;
    if (lg == 0){
      c.u[0] = pk(f2bf(SSC*Wih[dr]), f2bf(SSC*Wih[192+dr]));
      c.u[1] = pk(f2bf(SSC*(bih[dr]+bhh[dr])), 0);
    }
    Ak2f[0] = c.s;
    c.u[0] = c.u[1] = 0u;
    if (lg == 0){
      c.u[0] = pk(f2bf(SSC*Wih[du]), f2bf(SSC*Wih[192+du]));
      c.u[1] = pk(f2bf(SSC*(bih[du]+bhh[du])), 0);
    }
    Ak2f[1] = c.s;
    c.u[0] = c.u[1] = 0u;
    if (lg == 0){
      c.u[1] = pk(f2bf(TSC*bhh[dn]), 0);
    }
    Ak2f[2] = c.s;
    c.u[0] = c.u[1] = 0u;
    if (lg == 0){
      c.u[0] = pk(f2bf(TSC*Wih[dn]), f2bf(TSC*Wih[192+dn]));
      c.u[1] = pk(f2bf(TSC*bih[dn]), 0);
    }
    Ak2f[3] = c.s;
  }
  // Wout^T fragments in registers (all waves, redundant wp maintenance)
  short8 AoR[2];
  #pragma unroll
  for (int kb = 0; kb < 2; ++kb){
    short8 f = (short8){0,0,0,0,0,0,0,0};
    if (lr < 2){
      #pragma unroll
      for (int j = 0; j < 8; ++j){
        int k = kb * 32 + lg * 8 + j;
        f[j] = (short)f2bf(SSC * Wout[k * 2 + lr]);
      }
    }
    AoR[kb] = f;
  }
  // hoisted tail-bias init vector ({bo0,bo1,0,0} in lg==0 lanes, zeros elsewhere)
  f32x4 aD0 = (f32x4){0,0,0,0};
  if (lg == 0){ aD0[0] = SSC * bout[0]; aD0[1] = SSC * bout[1]; }
  // hoisted B2 invariants: high word (1.0bf in k=66 slot) and zero tail
  const unsigned b2hi = (lg == 0) ? 0x00003F80u : 0u;
  const bool dostore = (lg == 0 && q == 0);
  // hoisted LDS byte offsets (double-buffer base added per phase)
  const int rd0 = lr * 128 + ((0  + 16 * lg) ^ swz);
  const int rd1 = lr * 128 + ((64 + 16 * lg) ^ swz);
  const int wr0 = lr * 128 + (colw ^ swz);
  __syncthreads();                                   // h(buf1) ready

  // ---------------- GRU rollout: 1 fused LDS-barrier/step, h double-buffered ----------------
  float wp0 = 0.f, wp1 = 0.f;
  float* outp = out + (size_t)(rowbase + lr) * 100;
  short8 B0 = *(const short8*)(sm_h + 2048 + rd0);
  short8 B1 = *(const short8*)(sm_h + 2048 + rd1);

  #pragma unroll 2
  for (int s = 0; s < TRAJ; ++s){
    char* bufW = sm_h + ((s & 1) << 11);   // step0 writes buf0, step1 buf1, ...
    short8 B2;
    {
      union { unsigned u[4]; short8 sv; } c;
      c.u[0] = (lg == 0) ? pkbf(wp0, wp1) : 0u;   // only the wp word varies per step
      c.u[1] = b2hi; c.u[2] = 0u; c.u[3] = 0u;
      B2 = c.sv;
    }
    f32x4 aR = (f32x4){0,0,0,0}, aU = (f32x4){0,0,0,0};
    f32x4 aN = (f32x4){0,0,0,0}, aI = (f32x4){0,0,0,0};
    aR = MFMA16(Ah[0][0], B0, aR);
    aR = MFMA16(Ah[0][1], B1, aR);
    aR = MFMA16(Ak2f[0],  B2, aR);
    aU = MFMA16(Ah[1][0], B0, aU);
    aU = MFMA16(Ah[1][1], B1, aU);
    aU = MFMA16(Ak2f[1],  B2, aU);
    aN = MFMA16(Ah[2][0], B0, aN);
    aN = MFMA16(Ah[2][1], B1, aN);
    aN = MFMA16(Ak2f[2],  B2, aN);
    aI = MFMA16(Ak2f[3],  B2, aI);
    f32x2 hA = gru_pair((f32x2){aR[0],aR[1]}, (f32x2){aU[0],aU[1]},
                        (f32x2){aN[0],aN[1]}, (f32x2){aI[0],aI[1]}, h2[0]);
    f32x2 hB = gru_pair((f32x2){aR[2],aR[3]}, (f32x2){aU[2],aU[3]},
                        (f32x2){aN[2],aN[3]}, (f32x2){aI[2],aI[3]}, h2[1]);
    h2[0] = hA; h2[1] = hB;
    *(uint2*)(bufW + wr0) =
        make_uint2(pkbf(hA[0], hA[1]), pkbf(hB[0], hB[1]));
    BAR();                                     // fused lgkmcnt(0)+s_barrier (LDS-only)
    short8 nB0 = *(const short8*)(bufW + rd0);
    short8 nB1 = *(const short8*)(bufW + rd1);
    f32x4 aD = aD0;
    aD = MFMA16(AoR[0], nB0, aD);
    aD = MFMA16(AoR[1], nB1, aD);
    {
      float ea = EXP2F(aD[0]), eb = EXP2F(aD[1]);
      float da = 1.f + ea, db = 1.f + eb;
      float rp = RCPF(da * db);
      wp0 += db * rp;                          // sigmoid(dx0)
      wp1 += da * rp;                          // sigmoid(dx1)
    }
    if (dostore)
      *(float2*)(outp + 2 * s) = make_float2(wp0, wp1);
    B0 = nB0; B1 = nB1;
  }
}

extern "C" void kernel_launch(void* const* d_in, const int* in_sizes, int n_in,
                              void* d_out, int out_size, void* d_ws, size_t ws_size,
                              hipStream_t stream) {
  (void)n_in; (void)out_size; (void)d_ws; (void)ws_size;
  const float* x    = (const float*)d_in[0];
  const float* W1   = (const float*)d_in[1];
  const float* b1   = (const float*)d_in[2];
  const float* W2   = (const float*)d_in[3];
  const float* b2   = (const float*)d_in[4];
  const float* Wih  = (const float*)d_in[5];
  const float* bih  = (const float*)d_in[6];
  const float* Whh  = (const float*)d_in[7];
  const float* bhh  = (const float*)d_in[8];
  const float* Wout = (const float*)d_in[9];
  const float* bout = (const float*)d_in[10];
  float* out = (float*)d_out;

  int nrows = in_sizes[0] / 256;
  int grid  = nrows / 16;                      // one 16-row group per 256-thread block
  gru_actor_kernel<<<dim3(grid), dim3(256), 0, stream>>>(
      x, W1, b1, W2, b2, Wih, bih, Whh, bhh, Wout, bout, out);
}